// Round 10
// baseline (950.634 us; speedup 1.0000x reference)
//
#include <hip/hip_runtime.h>
#include <math.h>

#define T_STEPS 5
#define BATCH 32

// async global->LDS: 16B per lane, dest = wave-uniform base + lane*16
__device__ __forceinline__ void stage16(const float* g, float* l) {
  __builtin_amdgcn_global_load_lds(
      (const __attribute__((address_space(1))) void*)g,
      (__attribute__((address_space(3))) void*)l, 16, 0, 0);
}

template <int CB>
__device__ __forceinline__ void fma_win(const float (&win)[6][8],
                                        const float* __restrict__ wp,
                                        float (&acc)[4][2][4]) {
#pragma unroll
  for (int kh = 0; kh < 5; ++kh)
#pragma unroll
    for (int kw = 0; kw < 5; ++kw) {
      float4 wv = *reinterpret_cast<const float4*>(wp + (kh * 5 + kw) * CB);
      float wa[4] = {wv.x, wv.y, wv.z, wv.w};
#pragma unroll
      for (int co = 0; co < 4; ++co)
#pragma unroll
        for (int r2 = 0; r2 < 2; ++r2)
#pragma unroll
          for (int c4 = 0; c4 < 4; ++c4)
            acc[co][r2][c4] =
                fmaf(win[kh + r2][kw + c4], wa[co], acc[co][r2][c4]);
    }
}

// ---------------------------------------------------------------------------
// LDS-staged 5x5 VALID conv, fp32, NCHW, padded input rows (WINP).
// Block tile: 32 rows x 16 cols x CB=16 co. tid = cog*64 + rg*4 + cg.
// Patch layout: 36 rows x 32 floats (8 granules of 16B per row), XOR-swizzled
// with f(row) = (row>>1)&7  [NOT row&7: read rows are 2*rg+rr, so row&7 spans
// only 4 same-parity values -> 2-way conflicts (measured r9). (row>>1)&7
// spans all 8 over rg=0..15 -> exactly 8 lanes/granule-position = conflict-
// free floor for both a4 (g=cg^f) and b4 (g=(cg+1)^f) reads].
// Staged by global_load_lds with PRE-SWIZZLED per-lane global source (LDS dest
// linear). Double-buffered; ONE __syncthreads per ci; reads+FMA unfenced.
// Weights staged in 16-ci chunks ([k][co] layout, wave-uniform b128
// broadcasts): caps weight-LDS at 25.6 KB so CIN=32 (conv3) fits 4 blocks/CU.
// Chunk restage at ci=16 is fenced by {barrier; write; barrier} where the
// first barrier certifies all waves finished fma(15) (old-chunk reads done).
// Rows clamped to HIN-1 (clamped rows feed only discarded outputs). CLAMPF
// adds flat clamp vs SRCMAX (conv1 reads real input; col bleed must stay
// in-bounds). conv2/3 col-bleed overruns stay inside d_ws.
// ---------------------------------------------------------------------------
template <int CIN, int CB, int HIN, int WINP, int HOUT, int WOUT, int TILES_W,
          bool CLAMPF, long SRCMAX>
__global__ __launch_bounds__(256, 4) void conv5_lds(
    const float* __restrict__ in, const float* __restrict__ wgt,
    float* __restrict__ out) {
  constexpr int WCHUNK = CIN < 16 ? CIN : 16;
  __shared__ __align__(16) float wlds[WCHUNK * 25 * CB];
  __shared__ __align__(16) float patch[2][1280];  // 288 granule slots + slack
  const int tid = threadIdx.x;
  const int n = blockIdx.z;
  const int cob = blockIdx.y;
  const int Cout = gridDim.y * CB;
  const int HW = HIN * WINP;

  const int th = blockIdx.x / TILES_W;
  const int twi = blockIdx.x - th * TILES_W;
  const int rowblk0 = th * 32;
  const int colblk0 = twi * 16;

  // ---- per-lane pre-swizzled global source offsets (floats) ----
  // issue A: granule G = tid; issue B (tid<32): G = 256 + tid
  long srcA, srcB = 0;
  {
    int G = tid;
    int row = G >> 3, q = G & 7;
    int cq = q ^ ((row >> 1) & 7);
    int gr = rowblk0 + row;
    gr = gr < HIN - 1 ? gr : HIN - 1;
    srcA = (long)n * CIN * HW + (long)gr * WINP + colblk0 + 4 * cq;
  }
  if (tid < 32) {
    int G = 256 + tid;
    int row = G >> 3, q = G & 7;
    int cq = q ^ ((row >> 1) & 7);
    int gr = rowblk0 + row;
    gr = gr < HIN - 1 ? gr : HIN - 1;
    srcB = (long)n * CIN * HW + (long)gr * WINP + colblk0 + 4 * cq;
  }
  const int wv = tid >> 6;  // wave id (wave-uniform)

  // issue stage(ci=0) immediately; hide behind weight staging
  {
    long oA = srcA;
    if (CLAMPF) oA = oA < SRCMAX ? oA : SRCMAX;
    stage16(in + oA, &patch[0][0] + wv * 256);
    if (tid < 32) {
      long oB = srcB;
      if (CLAMPF) oB = oB < SRCMAX ? oB : SRCMAX;
      stage16(in + oB, &patch[0][0] + 1024);
    }
  }
  // weight chunk 0
  for (int i = tid; i < WCHUNK * 25 * CB; i += 256) {
    int co = i & (CB - 1);
    int k = i / CB;
    wlds[i] = wgt[(cob * CB + co) * (CIN * 25) + k];
  }

  const int cog = tid >> 6;
  const int rg2 = ((tid >> 2) & 15) * 2;
  const int cg = tid & 3;

  float acc[4][2][4];
#pragma unroll
  for (int a = 0; a < 4; ++a)
#pragma unroll
    for (int b = 0; b < 2; ++b)
#pragma unroll
      for (int c = 0; c < 4; ++c) acc[a][b][c] = 0.f;

  for (int ci = 0; ci < CIN; ++ci) {
    if (CIN > 16 && ci == 16) {  // restage weight chunk 1
      __syncthreads();  // all waves done reading chunk-0 weights (fma 15)
      for (int i = tid; i < 16 * 25 * CB; i += 256) {
        int co = i & (CB - 1);
        int k = i / CB;
        wlds[i] = wgt[(cob * CB + co) * (CIN * 25) + 16 * 25 + k];
      }
    }
    __syncthreads();  // stage(ci) landed; prev reads done; weights visible
    if (ci + 1 < CIN) {  // prefetch next ci into other buffer
      long oA = srcA + (long)(ci + 1) * HW;
      if (CLAMPF) oA = oA < SRCMAX ? oA : SRCMAX;
      stage16(in + oA, &patch[(ci + 1) & 1][0] + wv * 256);
      if (tid < 32) {
        long oB = srcB + (long)(ci + 1) * HW;
        if (CLAMPF) oB = oB < SRCMAX ? oB : SRCMAX;
        stage16(in + oB, &patch[(ci + 1) & 1][0] + 1024);
      }
    }

    // swizzled window reads; unfenced -> compiler pipelines into FMAs
    float win[6][8];
    const float* pb = &patch[ci & 1][0];
#pragma unroll
    for (int rr = 0; rr < 6; ++rr) {
      int row = rg2 + rr;
      int f = (row >> 1) & 7;
      float4 a4 = *reinterpret_cast<const float4*>(pb + row * 32 +
                                                   ((cg ^ f) << 2));
      float4 b4 = *reinterpret_cast<const float4*>(pb + row * 32 +
                                                   (((cg + 1) ^ f) << 2));
      win[rr][0] = a4.x; win[rr][1] = a4.y; win[rr][2] = a4.z;
      win[rr][3] = a4.w; win[rr][4] = b4.x; win[rr][5] = b4.y;
      win[rr][6] = b4.z; win[rr][7] = b4.w;
    }
    fma_win<CB>(win, &wlds[(ci & 15) * 25 * CB + cog * 4], acc);
  }

#pragma unroll
  for (int co = 0; co < 4; ++co) {
    int coG = cob * CB + cog * 4 + co;
    float* op = out + ((long)n * Cout + coG) * (HOUT * WOUT);
#pragma unroll
    for (int r2 = 0; r2 < 2; ++r2) {
      int ho = rowblk0 + rg2 + r2;
      if (ho < HOUT) {
#pragma unroll
        for (int c4 = 0; c4 < 4; ++c4) {
          int wo = colblk0 + cg * 4 + c4;
          if (wo < WOUT) op[ho * WOUT + wo] = acc[co][r2][c4];
        }
      }
    }
  }
}

// conv4: (160,32,12,12) -> (160,64,8,8). Weights [k][co16] in LDS,
// single-buffer window (L2-hot input), simple schedule.
__global__ __launch_bounds__(256) void conv4_rb(const float* __restrict__ in,
                                                const float* __restrict__ wgt,
                                                float* __restrict__ out) {
  __shared__ __align__(16) float wlds[32 * 25 * 16];
  const int tid = threadIdx.x;
  const int cob = blockIdx.x;  // 0..3
  const int n = blockIdx.y;    // 0..159
  for (int i = tid; i < 32 * 25 * 16; i += 256) {
    int co = i & 15;
    int k = i >> 4;
    wlds[i] = wgt[(cob * 16 + co) * 800 + k];
  }
  __syncthreads();
  const int px = tid & 63;
  const int cog = tid >> 6;
  const int r = px >> 3, c = px & 7;
  float acc[4] = {0.f, 0.f, 0.f, 0.f};
  const float* ip = in + (long)n * 32 * 144 + r * 12 + c;
  for (int ci = 0; ci < 32; ++ci) {
    float win[25];
#pragma unroll
    for (int kh = 0; kh < 5; ++kh)
#pragma unroll
      for (int kw = 0; kw < 5; ++kw) win[kh * 5 + kw] = ip[kh * 12 + kw];
    ip += 144;
    const float* wp = &wlds[ci * 400 + cog * 4];
#pragma unroll
    for (int kk = 0; kk < 25; ++kk) {
      float4 wv = *reinterpret_cast<const float4*>(wp + kk * 16);
      acc[0] = fmaf(win[kk], wv.x, acc[0]);
      acc[1] = fmaf(win[kk], wv.y, acc[1]);
      acc[2] = fmaf(win[kk], wv.z, acc[2]);
      acc[3] = fmaf(win[kk], wv.w, acc[3]);
    }
  }
  float* op = out + ((long)n * 64 + cob * 16 + cog * 4) * 64 + px;
#pragma unroll
  for (int j = 0; j < 4; ++j) op[j * 64] = acc[j];
}

// BN stats: two-stage deterministic partial sums in double ------------------
__global__ __launch_bounds__(256) void bn_partial(
    const float* __restrict__ y, int C, int M, int HW, double inv_hw,
    double* __restrict__ psum, double* __restrict__ psq, int S) {
  const int c = blockIdx.x / S;
  const int s = blockIdx.x - c * S;
  const int tid = threadIdx.x;
  double sum = 0.0, sumsq = 0.0;
  for (int i = s * 256 + tid; i < M; i += S * 256) {
    int n = (int)((double)i * inv_hw);
    int hw = i - n * HW;
    if (hw < 0) { n--; hw += HW; }
    else if (hw >= HW) { n++; hw -= HW; }
    float v = y[((long)n * C + c) * (long)HW + hw];
    sum += (double)v;
    sumsq += (double)v * (double)v;
  }
  __shared__ double ls[256], ls2[256];
  ls[tid] = sum;
  ls2[tid] = sumsq;
  __syncthreads();
  for (int off = 128; off > 0; off >>= 1) {
    if (tid < off) {
      ls[tid] += ls[tid + off];
      ls2[tid] += ls2[tid + off];
    }
    __syncthreads();
  }
  if (tid == 0) {
    psum[blockIdx.x] = ls[0];
    psq[blockIdx.x] = ls2[0];
  }
}

__global__ void bn_finalize(const double* __restrict__ psum,
                            const double* __restrict__ psq,
                            const float* __restrict__ gamma,
                            const float* __restrict__ beta,
                            float* __restrict__ scale,
                            float* __restrict__ shift, int C, int S,
                            double invM) {
  int c = threadIdx.x;
  if (c >= C) return;
  double s = 0.0, s2 = 0.0;
  for (int i = 0; i < S; ++i) {
    s += psum[c * S + i];
    s2 += psq[c * S + i];
  }
  double m = s * invM;
  double var = s2 * invM - m * m;
  double r = 1.0 / sqrt(var + 1e-5);
  double sc = (double)gamma[c] * r;
  scale[c] = (float)sc;
  shift[c] = (float)((double)beta[c] - m * sc);
}

// Fused BN-affine + 5-step PLIF + 2x2 maxpool; padded pool rows (PWp). ------
__global__ __launch_bounds__(256) void plif_pool(
    const float* __restrict__ y, const float* __restrict__ scale,
    const float* __restrict__ shift, const float* __restrict__ wlif,
    float* __restrict__ p, int C, int H, int W, int PH, int PW, int PWp,
    long t_stride) {
  int idx = blockIdx.x * 256 + threadIdx.x;
  int total = BATCH * C * PH * PWp;
  if (idx >= total) return;
  int pw = idx % PWp;
  int t2 = idx / PWp;
  int ph = t2 % PH;
  t2 /= PH;
  int c = t2 % C;
  int b = t2 / C;
  const long pstr = (long)BATCH * C * PH * PWp;
  const long pbase = (((long)b * C + c) * PH + ph) * PWp + pw;
  if (pw >= PW) {
#pragma unroll
    for (int t = 0; t < T_STEPS; ++t) p[t * pstr + pbase] = 0.f;
    return;
  }
  const float sc = scale[c], sh = shift[c];
  const float decay = 1.f / (1.f + expf(-wlif[0]));
  const long base = (((long)b * C + c) * H + 2 * ph) * W + 2 * pw;
  float v0 = 0.f, v1 = 0.f, v2 = 0.f, v3 = 0.f;
#pragma unroll
  for (int t = 0; t < T_STEPS; ++t) {
    const float* yp = y + t * t_stride + base;
    float x0 = yp[0] * sc + sh;
    float x1 = yp[1] * sc + sh;
    float x2 = yp[W] * sc + sh;
    float x3 = yp[W + 1] * sc + sh;
    v0 += (x0 - v0) * decay;
    v1 += (x1 - v1) * decay;
    v2 += (x2 - v2) * decay;
    v3 += (x3 - v3) * decay;
    float s0 = (v0 >= 1.f) ? 1.f : 0.f;
    float s1 = (v1 >= 1.f) ? 1.f : 0.f;
    float s2 = (v2 >= 1.f) ? 1.f : 0.f;
    float s3 = (v3 >= 1.f) ? 1.f : 0.f;
    v0 = (v0 >= 1.f) ? 0.f : v0;
    v1 = (v1 >= 1.f) ? 0.f : v1;
    v2 = (v2 >= 1.f) ? 0.f : v2;
    v3 = (v3 >= 1.f) ? 0.f : v3;
    p[t * pstr + pbase] = fmaxf(fmaxf(s0, s1), fmaxf(s2, s3));
  }
}

// fc1: n-tiled GEMM, 8 batch rows staged in LDS -----------------------------
__global__ __launch_bounds__(256, 2) void fc1_tiled(
    const float* __restrict__ x, const float* __restrict__ w,
    float* __restrict__ out) {
  __shared__ __align__(16) float xs[8][1024];
  const int tid = threadIdx.x;
  const int n0 = blockIdx.y * 8;
  const int o = blockIdx.x * 256 + tid;
  for (int i = tid; i < 8 * 1024; i += 256) {
    int nn = i >> 10, k = i & 1023;
    xs[nn][k] = x[(long)(n0 + nn) * 1024 + k];
  }
  __syncthreads();
  const float4* wr = reinterpret_cast<const float4*>(w + (long)o * 1024);
  float acc[8] = {0.f, 0.f, 0.f, 0.f, 0.f, 0.f, 0.f, 0.f};
  for (int k4 = 0; k4 < 256; ++k4) {
    float4 w4 = wr[k4];
#pragma unroll
    for (int nn = 0; nn < 8; ++nn) {
      float4 xv = *reinterpret_cast<const float4*>(&xs[nn][k4 * 4]);
      acc[nn] += w4.x * xv.x + w4.y * xv.y + w4.z * xv.z + w4.w * xv.w;
    }
  }
#pragma unroll
  for (int nn = 0; nn < 8; ++nn) out[(long)(n0 + nn) * 1024 + o] = acc[nn];
}

// fc2 ----------------------------------------------------------------------
__global__ __launch_bounds__(256) void fc_kernel(const float* __restrict__ x,
                                                 const float* __restrict__ w,
                                                 float* __restrict__ out,
                                                 int K, int O, int obpn) {
  int n = blockIdx.x / obpn;
  int o = (blockIdx.x - n * obpn) * 256 + threadIdx.x;
  if (o >= O) return;
  const float4* xr = reinterpret_cast<const float4*>(x + (long)n * K);
  const float4* wr = reinterpret_cast<const float4*>(w + (long)o * K);
  float acc = 0.f;
  for (int k = 0; k < K / 4; ++k) {
    float4 a = xr[k];
    float4 b = wr[k];
    acc += a.x * b.x + a.y * b.y + a.z * b.z + a.w * b.w;
  }
  out[(long)n * O + o] = acc;
}

__global__ __launch_bounds__(256) void plif_fc(const float* __restrict__ h,
                                               const float* __restrict__ bias,
                                               const float* __restrict__ wlif,
                                               float* __restrict__ s_out,
                                               int F) {
  int idx = blockIdx.x * 256 + threadIdx.x;
  if (idx >= BATCH * F) return;
  int f = idx % F;
  int b = idx / F;
  const float decay = 1.f / (1.f + expf(-wlif[0]));
  const float bi = bias[f];
  float v = 0.f;
#pragma unroll
  for (int t = 0; t < T_STEPS; ++t) {
    long off = ((long)(t * BATCH + b)) * F + f;
    float x = h[off] + bi;
    v += (x - v) * decay;
    float s = (v >= 1.f) ? 1.f : 0.f;
    v = (v >= 1.f) ? 0.f : v;
    s_out[off] = s;
  }
}

__global__ __launch_bounds__(256) void plif_mean(const float* __restrict__ h,
                                                 const float* __restrict__ bias,
                                                 const float* __restrict__ wlif,
                                                 float* __restrict__ out,
                                                 int O) {
  int idx = blockIdx.x * 256 + threadIdx.x;
  if (idx >= BATCH * O) return;
  int o = idx % O;
  int b = idx / O;
  const float decay = 1.f / (1.f + expf(-wlif[0]));
  const float bi = bias[o];
  float v = 0.f, sum = 0.f;
#pragma unroll
  for (int t = 0; t < T_STEPS; ++t) {
    float x = h[(long)(t * BATCH + b) * O + o] + bi;
    v += (x - v) * decay;
    float s = (v >= 1.f) ? 1.f : 0.f;
    v = (v >= 1.f) ? 0.f : v;
    sum += s;
  }
  out[(long)b * O + o] = sum / 5.0f;
}

// ---------------------------------------------------------------------------
extern "C" void kernel_launch(void* const* d_in, const int* in_sizes, int n_in,
                              void* d_out, int out_size, void* d_ws,
                              size_t ws_size, hipStream_t stream) {
  const float* x = (const float*)d_in[0];
  const float* wc1 = (const float*)d_in[1];
  const float* wc2 = (const float*)d_in[2];
  const float* wc3 = (const float*)d_in[3];
  const float* wc4 = (const float*)d_in[4];
  const float* g1 = (const float*)d_in[5];
  const float* b1 = (const float*)d_in[6];
  const float* g2 = (const float*)d_in[7];
  const float* b2 = (const float*)d_in[8];
  const float* g3 = (const float*)d_in[9];
  const float* b3 = (const float*)d_in[10];
  const float* g4 = (const float*)d_in[11];
  const float* b4 = (const float*)d_in[12];
  const float* wl1 = (const float*)d_in[13];
  const float* wl2 = (const float*)d_in[14];
  const float* wl3 = (const float*)d_in[15];
  const float* wl4 = (const float*)d_in[16];
  const float* wl5 = (const float*)d_in[17];
  const float* wl6 = (const float*)d_in[18];
  const float* fc1w = (const float*)d_in[19];
  const float* fc1b = (const float*)d_in[20];
  const float* fc2w = (const float*)d_in[21];
  const float* fc2b = (const float*)d_in[22];
  float* out = (float*)d_out;

  // Workspace: Y 68,894,720 B | P 40,632,320 B (padded pool) | stats
  // (conv col-bleed may read a few dozen floats past P into stats: harmless)
  char* ws = (char*)d_ws;
  float* Y = (float*)ws;
  float* P = (float*)(ws + 68894720);
  char* Sb = ws + 68894720 + 40632320;
  double* psum = (double*)Sb;
  double* psq = psum + 64 * 32;
  float* scale = (float*)(psq + 64 * 32);
  float* shift = scale + 64;

  const int S = 32;

  // ---- block 1: conv1 on B=32 only (input replicated over T) ----
  conv5_lds<3, 16, 128, 128, 124, 124, 8, true, (long)32 * 3 * 128 * 128 - 4>
      <<<dim3(4 * 8, 1, 32), 256, 0, stream>>>(x, wc1, Y);
  {
    int HW = 124 * 124, M = 32 * HW;
    bn_partial<<<16 * S, 256, 0, stream>>>(Y, 16, M, HW, 1.0 / HW, psum, psq, S);
    bn_finalize<<<1, 64, 0, stream>>>(psum, psq, g1, b1, scale, shift, 16, S,
                                      1.0 / (double)M);
  }
  {  // pool1 out: (5,32,16,62,PWp=64)
    int total = BATCH * 16 * 62 * 64;
    plif_pool<<<(total + 255) / 256, 256, 0, stream>>>(
        Y, scale, shift, wl1, P, 16, 124, 124, 62, 62, 64, 0L);
  }

  // ---- block 2: conv2 (160,16,62x64p) -> (160,32,58,58) ----
  conv5_lds<16, 16, 62, 64, 58, 58, 4, false, 0>
      <<<dim3(2 * 4, 2, 160), 256, 0, stream>>>(P, wc2, Y);
  {
    int HW = 58 * 58, M = 160 * HW;
    bn_partial<<<32 * S, 256, 0, stream>>>(Y, 32, M, HW, 1.0 / HW, psum, psq, S);
    bn_finalize<<<1, 64, 0, stream>>>(psum, psq, g2, b2, scale, shift, 32, S,
                                      1.0 / (double)M);
  }
  {  // pool2 out: (5,32,32,29,PWp=32)
    int total = BATCH * 32 * 29 * 32;
    plif_pool<<<(total + 255) / 256, 256, 0, stream>>>(
        Y, scale, shift, wl2, P, 32, 58, 58, 29, 29, 32,
        (long)BATCH * 32 * 58 * 58);
  }

  // ---- block 3: conv3 (160,32,29x32p) -> (160,32,25,25) ----
  conv5_lds<32, 16, 29, 32, 25, 25, 2, false, 0>
      <<<dim3(1 * 2, 2, 160), 256, 0, stream>>>(P, wc3, Y);
  {
    int HW = 25 * 25, M = 160 * HW;
    bn_partial<<<32 * S, 256, 0, stream>>>(Y, 32, M, HW, 1.0 / HW, psum, psq, S);
    bn_finalize<<<1, 64, 0, stream>>>(psum, psq, g3, b3, scale, shift, 32, S,
                                      1.0 / (double)M);
  }
  {  // pool3 out: (5,32,32,12,12)
    int total = BATCH * 32 * 12 * 12;
    plif_pool<<<(total + 255) / 256, 256, 0, stream>>>(
        Y, scale, shift, wl3, P, 32, 25, 25, 12, 12, 12,
        (long)BATCH * 32 * 25 * 25);
  }

  // ---- block 4: conv4 (160,32,12,12) -> (160,64,8,8) ----
  conv4_rb<<<dim3(4, 160), 256, 0, stream>>>(P, wc4, Y);
  {
    int HW = 8 * 8, M = 160 * HW;
    bn_partial<<<64 * S, 256, 0, stream>>>(Y, 64, M, HW, 1.0 / HW, psum, psq, S);
    bn_finalize<<<1, 64, 0, stream>>>(psum, psq, g4, b4, scale, shift, 64, S,
                                      1.0 / (double)M);
  }
  {  // pool4 out: (5,32,64,4,4)
    int total = BATCH * 64 * 4 * 4;
    plif_pool<<<(total + 255) / 256, 256, 0, stream>>>(
        Y, scale, shift, wl4, P, 64, 8, 8, 4, 4, 4, (long)BATCH * 64 * 8 * 8);
  }

  // ---- FC head ----
  float* h1 = Y;
  float* s1 = P;
  float* h2 = Y + 163840;
  fc1_tiled<<<dim3(4, 20), 256, 0, stream>>>(P, fc1w, h1);
  plif_fc<<<(BATCH * 1024 + 255) / 256, 256, 0, stream>>>(h1, fc1b, wl5, s1,
                                                          1024);
  fc_kernel<<<160 * 1, 256, 0, stream>>>(s1, fc2w, h2, 1024, 10, 1);
  plif_mean<<<(BATCH * 10 + 255) / 256, 256, 0, stream>>>(h2, fc2b, wl6, out,
                                                          10);
}

// Round 11
// 868.910 us; speedup vs baseline: 1.0941x; 1.0941x over previous
//
#include <hip/hip_runtime.h>
#include <math.h>

#define T_STEPS 5
#define BATCH 32

// async global->LDS: 16B per lane, dest = wave-uniform base + lane*16
__device__ __forceinline__ void stage16(const float* g, float* l) {
  __builtin_amdgcn_global_load_lds(
      (const __attribute__((address_space(1))) void*)g,
      (__attribute__((address_space(3))) void*)l, 16, 0, 0);
}

template <int CB>
__device__ __forceinline__ void fma_win(const float (&win)[6][8],
                                        const float* __restrict__ wp,
                                        float (&acc)[4][2][4]) {
#pragma unroll
  for (int kh = 0; kh < 5; ++kh)
#pragma unroll
    for (int kw = 0; kw < 5; ++kw) {
      float4 wv = *reinterpret_cast<const float4*>(wp + (kh * 5 + kw) * CB);
      float wa[4] = {wv.x, wv.y, wv.z, wv.w};
#pragma unroll
      for (int co = 0; co < 4; ++co)
#pragma unroll
        for (int r2 = 0; r2 < 2; ++r2)
#pragma unroll
          for (int c4 = 0; c4 < 4; ++c4)
            acc[co][r2][c4] =
                fmaf(win[kh + r2][kw + c4], wa[co], acc[co][r2][c4]);
    }
}

// ---------------------------------------------------------------------------
// LDS-staged 5x5 VALID conv, fp32, NCHW, padded input rows (WINP).
// Block tile: 32 rows x 16 cols x CB=16 co. tid = cog*64 + rg*4 + cg.
// Patch layout: 36 rows x 32 floats (8 granules of 16B per row), XOR-swizzled
// with f(row) = (row>>1)&7 (read rows are 2*rg+rr; this key spans all 8
// values over rg -> 8 lanes/granule-position = conflict-free b128 floor).
// Staged by global_load_lds with PRE-SWIZZLED per-lane global source (LDS dest
// linear). Double-buffered; ONE __syncthreads per ci; reads+FMA unfenced.
// Weights staged in 16-ci chunks ([k][co] layout, wave-uniform b128
// broadcasts): caps weight-LDS at 25.6 KB (conv3 fits more blocks/CU).
// __launch_bounds__(256,3): VGPR cap ~85 fits the ~68-reg allocation.
// (256,4) caps at 64 -> spills win/acc to scratch: r10 measured 578MB FETCH /
// 442MB WRITE / VALUBusy 4% on conv1. DO NOT raise the min-waves bound.
// Rows clamped to HIN-1 (clamped rows feed only discarded outputs). CLAMPF
// adds flat clamp vs SRCMAX (conv1 reads real input; col bleed must stay
// in-bounds). conv2/3 col-bleed overruns stay inside d_ws.
// ---------------------------------------------------------------------------
template <int CIN, int CB, int HIN, int WINP, int HOUT, int WOUT, int TILES_W,
          bool CLAMPF, long SRCMAX>
__global__ __launch_bounds__(256, 3) void conv5_lds(
    const float* __restrict__ in, const float* __restrict__ wgt,
    float* __restrict__ out) {
  constexpr int WCHUNK = CIN < 16 ? CIN : 16;
  __shared__ __align__(16) float wlds[WCHUNK * 25 * CB];
  __shared__ __align__(16) float patch[2][1280];  // 288 granule slots + slack
  const int tid = threadIdx.x;
  const int n = blockIdx.z;
  const int cob = blockIdx.y;
  const int Cout = gridDim.y * CB;
  const int HW = HIN * WINP;

  const int th = blockIdx.x / TILES_W;
  const int twi = blockIdx.x - th * TILES_W;
  const int rowblk0 = th * 32;
  const int colblk0 = twi * 16;

  // ---- per-lane pre-swizzled global source offsets (floats) ----
  // issue A: granule G = tid; issue B (tid<32): G = 256 + tid
  long srcA, srcB = 0;
  {
    int G = tid;
    int row = G >> 3, q = G & 7;
    int cq = q ^ ((row >> 1) & 7);
    int gr = rowblk0 + row;
    gr = gr < HIN - 1 ? gr : HIN - 1;
    srcA = (long)n * CIN * HW + (long)gr * WINP + colblk0 + 4 * cq;
  }
  if (tid < 32) {
    int G = 256 + tid;
    int row = G >> 3, q = G & 7;
    int cq = q ^ ((row >> 1) & 7);
    int gr = rowblk0 + row;
    gr = gr < HIN - 1 ? gr : HIN - 1;
    srcB = (long)n * CIN * HW + (long)gr * WINP + colblk0 + 4 * cq;
  }
  const int wv = tid >> 6;  // wave id (wave-uniform)

  // issue stage(ci=0) immediately; hide behind weight staging
  {
    long oA = srcA;
    if (CLAMPF) oA = oA < SRCMAX ? oA : SRCMAX;
    stage16(in + oA, &patch[0][0] + wv * 256);
    if (tid < 32) {
      long oB = srcB;
      if (CLAMPF) oB = oB < SRCMAX ? oB : SRCMAX;
      stage16(in + oB, &patch[0][0] + 1024);
    }
  }
  // weight chunk 0
  for (int i = tid; i < WCHUNK * 25 * CB; i += 256) {
    int co = i & (CB - 1);
    int k = i / CB;
    wlds[i] = wgt[(cob * CB + co) * (CIN * 25) + k];
  }

  const int cog = tid >> 6;
  const int rg2 = ((tid >> 2) & 15) * 2;
  const int cg = tid & 3;

  float acc[4][2][4];
#pragma unroll
  for (int a = 0; a < 4; ++a)
#pragma unroll
    for (int b = 0; b < 2; ++b)
#pragma unroll
      for (int c = 0; c < 4; ++c) acc[a][b][c] = 0.f;

  for (int ci = 0; ci < CIN; ++ci) {
    if (CIN > 16 && ci == 16) {  // restage weight chunk 1
      __syncthreads();  // all waves done reading chunk-0 weights (fma 15)
      for (int i = tid; i < 16 * 25 * CB; i += 256) {
        int co = i & (CB - 1);
        int k = i / CB;
        wlds[i] = wgt[(cob * CB + co) * (CIN * 25) + 16 * 25 + k];
      }
    }
    __syncthreads();  // stage(ci) landed; prev reads done; weights visible
    if (ci + 1 < CIN) {  // prefetch next ci into other buffer
      long oA = srcA + (long)(ci + 1) * HW;
      if (CLAMPF) oA = oA < SRCMAX ? oA : SRCMAX;
      stage16(in + oA, &patch[(ci + 1) & 1][0] + wv * 256);
      if (tid < 32) {
        long oB = srcB + (long)(ci + 1) * HW;
        if (CLAMPF) oB = oB < SRCMAX ? oB : SRCMAX;
        stage16(in + oB, &patch[(ci + 1) & 1][0] + 1024);
      }
    }

    // swizzled window reads; unfenced -> compiler pipelines into FMAs
    float win[6][8];
    const float* pb = &patch[ci & 1][0];
#pragma unroll
    for (int rr = 0; rr < 6; ++rr) {
      int row = rg2 + rr;
      int f = (row >> 1) & 7;
      float4 a4 = *reinterpret_cast<const float4*>(pb + row * 32 +
                                                   ((cg ^ f) << 2));
      float4 b4 = *reinterpret_cast<const float4*>(pb + row * 32 +
                                                   (((cg + 1) ^ f) << 2));
      win[rr][0] = a4.x; win[rr][1] = a4.y; win[rr][2] = a4.z;
      win[rr][3] = a4.w; win[rr][4] = b4.x; win[rr][5] = b4.y;
      win[rr][6] = b4.z; win[rr][7] = b4.w;
    }
    fma_win<CB>(win, &wlds[(ci & 15) * 25 * CB + cog * 4], acc);
  }

#pragma unroll
  for (int co = 0; co < 4; ++co) {
    int coG = cob * CB + cog * 4 + co;
    float* op = out + ((long)n * Cout + coG) * (HOUT * WOUT);
#pragma unroll
    for (int r2 = 0; r2 < 2; ++r2) {
      int ho = rowblk0 + rg2 + r2;
      if (ho < HOUT) {
#pragma unroll
        for (int c4 = 0; c4 < 4; ++c4) {
          int wo = colblk0 + cg * 4 + c4;
          if (wo < WOUT) op[ho * WOUT + wo] = acc[co][r2][c4];
        }
      }
    }
  }
}

// conv4: (160,32,12,12) -> (160,64,8,8). Weights [k][co16] in LDS,
// single-buffer window (L2-hot input), simple schedule.
__global__ __launch_bounds__(256) void conv4_rb(const float* __restrict__ in,
                                                const float* __restrict__ wgt,
                                                float* __restrict__ out) {
  __shared__ __align__(16) float wlds[32 * 25 * 16];
  const int tid = threadIdx.x;
  const int cob = blockIdx.x;  // 0..3
  const int n = blockIdx.y;    // 0..159
  for (int i = tid; i < 32 * 25 * 16; i += 256) {
    int co = i & 15;
    int k = i >> 4;
    wlds[i] = wgt[(cob * 16 + co) * 800 + k];
  }
  __syncthreads();
  const int px = tid & 63;
  const int cog = tid >> 6;
  const int r = px >> 3, c = px & 7;
  float acc[4] = {0.f, 0.f, 0.f, 0.f};
  const float* ip = in + (long)n * 32 * 144 + r * 12 + c;
  for (int ci = 0; ci < 32; ++ci) {
    float win[25];
#pragma unroll
    for (int kh = 0; kh < 5; ++kh)
#pragma unroll
      for (int kw = 0; kw < 5; ++kw) win[kh * 5 + kw] = ip[kh * 12 + kw];
    ip += 144;
    const float* wp = &wlds[ci * 400 + cog * 4];
#pragma unroll
    for (int kk = 0; kk < 25; ++kk) {
      float4 wv = *reinterpret_cast<const float4*>(wp + kk * 16);
      acc[0] = fmaf(win[kk], wv.x, acc[0]);
      acc[1] = fmaf(win[kk], wv.y, acc[1]);
      acc[2] = fmaf(win[kk], wv.z, acc[2]);
      acc[3] = fmaf(win[kk], wv.w, acc[3]);
    }
  }
  float* op = out + ((long)n * 64 + cob * 16 + cog * 4) * 64 + px;
#pragma unroll
  for (int j = 0; j < 4; ++j) op[j * 64] = acc[j];
}

// BN stats: two-stage deterministic partial sums in double ------------------
__global__ __launch_bounds__(256) void bn_partial(
    const float* __restrict__ y, int C, int M, int HW, double inv_hw,
    double* __restrict__ psum, double* __restrict__ psq, int S) {
  const int c = blockIdx.x / S;
  const int s = blockIdx.x - c * S;
  const int tid = threadIdx.x;
  double sum = 0.0, sumsq = 0.0;
  for (int i = s * 256 + tid; i < M; i += S * 256) {
    int n = (int)((double)i * inv_hw);
    int hw = i - n * HW;
    if (hw < 0) { n--; hw += HW; }
    else if (hw >= HW) { n++; hw -= HW; }
    float v = y[((long)n * C + c) * (long)HW + hw];
    sum += (double)v;
    sumsq += (double)v * (double)v;
  }
  __shared__ double ls[256], ls2[256];
  ls[tid] = sum;
  ls2[tid] = sumsq;
  __syncthreads();
  for (int off = 128; off > 0; off >>= 1) {
    if (tid < off) {
      ls[tid] += ls[tid + off];
      ls2[tid] += ls2[tid + off];
    }
    __syncthreads();
  }
  if (tid == 0) {
    psum[blockIdx.x] = ls[0];
    psq[blockIdx.x] = ls2[0];
  }
}

__global__ void bn_finalize(const double* __restrict__ psum,
                            const double* __restrict__ psq,
                            const float* __restrict__ gamma,
                            const float* __restrict__ beta,
                            float* __restrict__ scale,
                            float* __restrict__ shift, int C, int S,
                            double invM) {
  int c = threadIdx.x;
  if (c >= C) return;
  double s = 0.0, s2 = 0.0;
  for (int i = 0; i < S; ++i) {
    s += psum[c * S + i];
    s2 += psq[c * S + i];
  }
  double m = s * invM;
  double var = s2 * invM - m * m;
  double r = 1.0 / sqrt(var + 1e-5);
  double sc = (double)gamma[c] * r;
  scale[c] = (float)sc;
  shift[c] = (float)((double)beta[c] - m * sc);
}

// Fused BN-affine + 5-step PLIF + 2x2 maxpool; padded pool rows (PWp). ------
__global__ __launch_bounds__(256) void plif_pool(
    const float* __restrict__ y, const float* __restrict__ scale,
    const float* __restrict__ shift, const float* __restrict__ wlif,
    float* __restrict__ p, int C, int H, int W, int PH, int PW, int PWp,
    long t_stride) {
  int idx = blockIdx.x * 256 + threadIdx.x;
  int total = BATCH * C * PH * PWp;
  if (idx >= total) return;
  int pw = idx % PWp;
  int t2 = idx / PWp;
  int ph = t2 % PH;
  t2 /= PH;
  int c = t2 % C;
  int b = t2 / C;
  const long pstr = (long)BATCH * C * PH * PWp;
  const long pbase = (((long)b * C + c) * PH + ph) * PWp + pw;
  if (pw >= PW) {
#pragma unroll
    for (int t = 0; t < T_STEPS; ++t) p[t * pstr + pbase] = 0.f;
    return;
  }
  const float sc = scale[c], sh = shift[c];
  const float decay = 1.f / (1.f + expf(-wlif[0]));
  const long base = (((long)b * C + c) * H + 2 * ph) * W + 2 * pw;
  float v0 = 0.f, v1 = 0.f, v2 = 0.f, v3 = 0.f;
#pragma unroll
  for (int t = 0; t < T_STEPS; ++t) {
    const float* yp = y + t * t_stride + base;
    float x0 = yp[0] * sc + sh;
    float x1 = yp[1] * sc + sh;
    float x2 = yp[W] * sc + sh;
    float x3 = yp[W + 1] * sc + sh;
    v0 += (x0 - v0) * decay;
    v1 += (x1 - v1) * decay;
    v2 += (x2 - v2) * decay;
    v3 += (x3 - v3) * decay;
    float s0 = (v0 >= 1.f) ? 1.f : 0.f;
    float s1 = (v1 >= 1.f) ? 1.f : 0.f;
    float s2 = (v2 >= 1.f) ? 1.f : 0.f;
    float s3 = (v3 >= 1.f) ? 1.f : 0.f;
    v0 = (v0 >= 1.f) ? 0.f : v0;
    v1 = (v1 >= 1.f) ? 0.f : v1;
    v2 = (v2 >= 1.f) ? 0.f : v2;
    v3 = (v3 >= 1.f) ? 0.f : v3;
    p[t * pstr + pbase] = fmaxf(fmaxf(s0, s1), fmaxf(s2, s3));
  }
}

// fc1: n-tiled GEMM, 8 batch rows staged in LDS -----------------------------
__global__ __launch_bounds__(256, 2) void fc1_tiled(
    const float* __restrict__ x, const float* __restrict__ w,
    float* __restrict__ out) {
  __shared__ __align__(16) float xs[8][1024];
  const int tid = threadIdx.x;
  const int n0 = blockIdx.y * 8;
  const int o = blockIdx.x * 256 + tid;
  for (int i = tid; i < 8 * 1024; i += 256) {
    int nn = i >> 10, k = i & 1023;
    xs[nn][k] = x[(long)(n0 + nn) * 1024 + k];
  }
  __syncthreads();
  const float4* wr = reinterpret_cast<const float4*>(w + (long)o * 1024);
  float acc[8] = {0.f, 0.f, 0.f, 0.f, 0.f, 0.f, 0.f, 0.f};
  for (int k4 = 0; k4 < 256; ++k4) {
    float4 w4 = wr[k4];
#pragma unroll
    for (int nn = 0; nn < 8; ++nn) {
      float4 xv = *reinterpret_cast<const float4*>(&xs[nn][k4 * 4]);
      acc[nn] += w4.x * xv.x + w4.y * xv.y + w4.z * xv.z + w4.w * xv.w;
    }
  }
#pragma unroll
  for (int nn = 0; nn < 8; ++nn) out[(long)(n0 + nn) * 1024 + o] = acc[nn];
}

// fc2 ----------------------------------------------------------------------
__global__ __launch_bounds__(256) void fc_kernel(const float* __restrict__ x,
                                                 const float* __restrict__ w,
                                                 float* __restrict__ out,
                                                 int K, int O, int obpn) {
  int n = blockIdx.x / obpn;
  int o = (blockIdx.x - n * obpn) * 256 + threadIdx.x;
  if (o >= O) return;
  const float4* xr = reinterpret_cast<const float4*>(x + (long)n * K);
  const float4* wr = reinterpret_cast<const float4*>(w + (long)o * K);
  float acc = 0.f;
  for (int k = 0; k < K / 4; ++k) {
    float4 a = xr[k];
    float4 b = wr[k];
    acc += a.x * b.x + a.y * b.y + a.z * b.z + a.w * b.w;
  }
  out[(long)n * O + o] = acc;
}

__global__ __launch_bounds__(256) void plif_fc(const float* __restrict__ h,
                                               const float* __restrict__ bias,
                                               const float* __restrict__ wlif,
                                               float* __restrict__ s_out,
                                               int F) {
  int idx = blockIdx.x * 256 + threadIdx.x;
  if (idx >= BATCH * F) return;
  int f = idx % F;
  int b = idx / F;
  const float decay = 1.f / (1.f + expf(-wlif[0]));
  const float bi = bias[f];
  float v = 0.f;
#pragma unroll
  for (int t = 0; t < T_STEPS; ++t) {
    long off = ((long)(t * BATCH + b)) * F + f;
    float x = h[off] + bi;
    v += (x - v) * decay;
    float s = (v >= 1.f) ? 1.f : 0.f;
    v = (v >= 1.f) ? 0.f : v;
    s_out[off] = s;
  }
}

__global__ __launch_bounds__(256) void plif_mean(const float* __restrict__ h,
                                                 const float* __restrict__ bias,
                                                 const float* __restrict__ wlif,
                                                 float* __restrict__ out,
                                                 int O) {
  int idx = blockIdx.x * 256 + threadIdx.x;
  if (idx >= BATCH * O) return;
  int o = idx % O;
  int b = idx / O;
  const float decay = 1.f / (1.f + expf(-wlif[0]));
  const float bi = bias[o];
  float v = 0.f, sum = 0.f;
#pragma unroll
  for (int t = 0; t < T_STEPS; ++t) {
    float x = h[(long)(t * BATCH + b) * O + o] + bi;
    v += (x - v) * decay;
    float s = (v >= 1.f) ? 1.f : 0.f;
    v = (v >= 1.f) ? 0.f : v;
    sum += s;
  }
  out[(long)b * O + o] = sum / 5.0f;
}

// ---------------------------------------------------------------------------
extern "C" void kernel_launch(void* const* d_in, const int* in_sizes, int n_in,
                              void* d_out, int out_size, void* d_ws,
                              size_t ws_size, hipStream_t stream) {
  const float* x = (const float*)d_in[0];
  const float* wc1 = (const float*)d_in[1];
  const float* wc2 = (const float*)d_in[2];
  const float* wc3 = (const float*)d_in[3];
  const float* wc4 = (const float*)d_in[4];
  const float* g1 = (const float*)d_in[5];
  const float* b1 = (const float*)d_in[6];
  const float* g2 = (const float*)d_in[7];
  const float* b2 = (const float*)d_in[8];
  const float* g3 = (const float*)d_in[9];
  const float* b3 = (const float*)d_in[10];
  const float* g4 = (const float*)d_in[11];
  const float* b4 = (const float*)d_in[12];
  const float* wl1 = (const float*)d_in[13];
  const float* wl2 = (const float*)d_in[14];
  const float* wl3 = (const float*)d_in[15];
  const float* wl4 = (const float*)d_in[16];
  const float* wl5 = (const float*)d_in[17];
  const float* wl6 = (const float*)d_in[18];
  const float* fc1w = (const float*)d_in[19];
  const float* fc1b = (const float*)d_in[20];
  const float* fc2w = (const float*)d_in[21];
  const float* fc2b = (const float*)d_in[22];
  float* out = (float*)d_out;

  // Workspace: Y 68,894,720 B | P 40,632,320 B (padded pool) | stats
  // (conv col-bleed may read a few dozen floats past P into stats: harmless)
  char* ws = (char*)d_ws;
  float* Y = (float*)ws;
  float* P = (float*)(ws + 68894720);
  char* Sb = ws + 68894720 + 40632320;
  double* psum = (double*)Sb;
  double* psq = psum + 64 * 32;
  float* scale = (float*)(psq + 64 * 32);
  float* shift = scale + 64;

  const int S = 32;

  // ---- block 1: conv1 on B=32 only (input replicated over T) ----
  conv5_lds<3, 16, 128, 128, 124, 124, 8, true, (long)32 * 3 * 128 * 128 - 4>
      <<<dim3(4 * 8, 1, 32), 256, 0, stream>>>(x, wc1, Y);
  {
    int HW = 124 * 124, M = 32 * HW;
    bn_partial<<<16 * S, 256, 0, stream>>>(Y, 16, M, HW, 1.0 / HW, psum, psq, S);
    bn_finalize<<<1, 64, 0, stream>>>(psum, psq, g1, b1, scale, shift, 16, S,
                                      1.0 / (double)M);
  }
  {  // pool1 out: (5,32,16,62,PWp=64)
    int total = BATCH * 16 * 62 * 64;
    plif_pool<<<(total + 255) / 256, 256, 0, stream>>>(
        Y, scale, shift, wl1, P, 16, 124, 124, 62, 62, 64, 0L);
  }

  // ---- block 2: conv2 (160,16,62x64p) -> (160,32,58,58) ----
  conv5_lds<16, 16, 62, 64, 58, 58, 4, false, 0>
      <<<dim3(2 * 4, 2, 160), 256, 0, stream>>>(P, wc2, Y);
  {
    int HW = 58 * 58, M = 160 * HW;
    bn_partial<<<32 * S, 256, 0, stream>>>(Y, 32, M, HW, 1.0 / HW, psum, psq, S);
    bn_finalize<<<1, 64, 0, stream>>>(psum, psq, g2, b2, scale, shift, 32, S,
                                      1.0 / (double)M);
  }
  {  // pool2 out: (5,32,32,29,PWp=32)
    int total = BATCH * 32 * 29 * 32;
    plif_pool<<<(total + 255) / 256, 256, 0, stream>>>(
        Y, scale, shift, wl2, P, 32, 58, 58, 29, 29, 32,
        (long)BATCH * 32 * 58 * 58);
  }

  // ---- block 3: conv3 (160,32,29x32p) -> (160,32,25,25) ----
  conv5_lds<32, 16, 29, 32, 25, 25, 2, false, 0>
      <<<dim3(1 * 2, 2, 160), 256, 0, stream>>>(P, wc3, Y);
  {
    int HW = 25 * 25, M = 160 * HW;
    bn_partial<<<32 * S, 256, 0, stream>>>(Y, 32, M, HW, 1.0 / HW, psum, psq, S);
    bn_finalize<<<1, 64, 0, stream>>>(psum, psq, g3, b3, scale, shift, 32, S,
                                      1.0 / (double)M);
  }
  {  // pool3 out: (5,32,32,12,12)
    int total = BATCH * 32 * 12 * 12;
    plif_pool<<<(total + 255) / 256, 256, 0, stream>>>(
        Y, scale, shift, wl3, P, 32, 25, 25, 12, 12, 12,
        (long)BATCH * 32 * 25 * 25);
  }

  // ---- block 4: conv4 (160,32,12,12) -> (160,64,8,8) ----
  conv4_rb<<<dim3(4, 160), 256, 0, stream>>>(P, wc4, Y);
  {
    int HW = 8 * 8, M = 160 * HW;
    bn_partial<<<64 * S, 256, 0, stream>>>(Y, 64, M, HW, 1.0 / HW, psum, psq, S);
    bn_finalize<<<1, 64, 0, stream>>>(psum, psq, g4, b4, scale, shift, 64, S,
                                      1.0 / (double)M);
  }
  {  // pool4 out: (5,32,64,4,4)
    int total = BATCH * 64 * 4 * 4;
    plif_pool<<<(total + 255) / 256, 256, 0, stream>>>(
        Y, scale, shift, wl4, P, 64, 8, 8, 4, 4, 4, (long)BATCH * 64 * 8 * 8);
  }

  // ---- FC head ----
  float* h1 = Y;
  float* s1 = P;
  float* h2 = Y + 163840;
  fc1_tiled<<<dim3(4, 20), 256, 0, stream>>>(P, fc1w, h1);
  plif_fc<<<(BATCH * 1024 + 255) / 256, 256, 0, stream>>>(h1, fc1b, wl5, s1,
                                                          1024);
  fc_kernel<<<160 * 1, 256, 0, stream>>>(s1, fc2w, h2, 1024, 10, 1);
  plif_mean<<<(BATCH * 10 + 255) / 256, 256, 0, stream>>>(h2, fc2b, wl6, out,
                                                          10);
}